// Round 17
// baseline (15.660 us; speedup 1.0000x reference)
//
#include <hip/hip_runtime.h>
#include <hip/hip_bf16.h>
#include <math.h>

// ThickCubeSimulator R16: R15 + selective z-QUAD merge in the outer region.
//  Error budget: 3.9e-3 used of 11.72e-3. z-curvature of vlos (the merge
//  error driver) peaks at small rcyl x high I — inside the 350 pc refined
//  zone. Outside it, merge 4 fine-z per eval (quad midpoints gz=-975+50l,
//  wgt 16, ONE eval/thread): outer deposit halves. Quad-midpoint set is
//  inversion-closed -> R15's symmetry stays exact. Refined center unchanged.
//  Pre-committed revert: absmax > 1e-2 -> restore R15, declare floor.

#define RES   80
#define NM    40
#define NPIXT (RES*RES)
#define NPIXB 8            // coarse pixels per block
#define NTPP  40           // threads per pixel
#define BLKT  320          // block size
#define NH    14           // harmonics (k=1..14) + DC -> 29 accumulators
#define RST   44           // Rbuf row stride (floats): 40 + pad, 16B multiple
#define RCUT2 (350.0f * 350.0f)  // refinement radius^2 (sky plane, pc^2)
#define C_KMS 299792.458f
#define F0GHZ 230.538f
#define LOG2E 1.44269504088896340736f
#define HPI   1.57079632679489662f
#define W1RAD 0.00981747704f     // 2*pi / 640 (rad per km/s)
#define PERIOD 640.0f

__device__ __forceinline__ float fast_exp2(float x) {
#if __has_builtin(__builtin_amdgcn_exp2f)
  return __builtin_amdgcn_exp2f(x);
#else
  return exp2f(x);
#endif
}
__device__ __forceinline__ float fast_rcp(float x) {
#if __has_builtin(__builtin_amdgcn_rcpf)
  return __builtin_amdgcn_rcpf(x);
#else
  return 1.0f / x;
#endif
}

// atan(u) for u>=0 via t=min(u,1/u) in [0,1], poly err ~1e-6 rad
__device__ __forceinline__ float atan_pos(float u, float uinv) {
  const float t  = fminf(u, uinv);
  const float t2 = t * t;
  float p = fmaf(t2, -0.0117212f, 0.05265332f);
  p = fmaf(t2, p, -0.11643287f);
  p = fmaf(t2, p, 0.19354346f);
  p = fmaf(t2, p, -0.33262347f);
  p = fmaf(t2, p, 0.99997726f);
  const float a = t * p;
  return (u <= 1.0f) ? a : (HPI - a);
}

// per-eval math at (x12, gxy2, y1ci, kcolw) for explicit gz; IO = wgt * I
#define CELLG(gzv, ANGO, IO, wgt) {                         \
    const float gz = (gzv);                                 \
    const float ry = fmaf(-si, gz, y1ci);                   \
    const float s2 = fmaf(ry, ry, x12);                     \
    const float rq = sqrtf(s2);                             \
    const float ri = fast_rcp(fmaxf(rq, 1e-30f));           \
    const float at = atan_pos(rq * irt, rt * ri);           \
    const float rs = sqrtf(fmaf(gz, gz, gxy2));             \
    ANGO = kcolw * (ri * at);                               \
    IO = (wgt) * fast_exp2(fmaf(rs, crd, li0)); }

__global__ __launch_bounds__(BLKT) void fourier_kernel(
    const float* __restrict__ p_inc, const float* __restrict__ p_rot,
    const float* __restrict__ p_lb,  const float* __restrict__ p_vs,
    const float* __restrict__ p_vmax, const float* __restrict__ p_rturn,
    const float* __restrict__ p_i0,  const float* __restrict__ p_rd,
    const float* __restrict__ freqs, float* __restrict__ out)
{
  __shared__ float TA[(NH + 1) * NM];          // 600 floats
  __shared__ float TB[(NH + 1) * NM];          // 600 floats
  __shared__ __align__(16) float Rbuf[NPIXB * 29 * RST];   // 10208 floats
  __shared__ float F[NPIXB * 32];              // reduced coeffs per pixel

  const int t   = threadIdx.x;
  const int blk = blockIdx.x;                  // 0..399
  const int p   = blk / (RES / NPIXB);         // coarse row 0..39 (half grid)
  const int q0  = (blk - p * (RES / NPIXB)) * NPIXB;

  // ---- per-thread params (uniform small args -> fast trig) ----
  const float inc = p_inc[0], rotv = p_rot[0], sig = p_lb[0];
  const float si = __sinf(inc), ci = __cosf(inc);
  const float cr = __cosf(rotv), sr = __sinf(rotv);
  const float kfac = -p_vmax[0] * 0.63661977236758134f * si;
  const float rt   = p_rturn[0];
  const float irt  = 1.0f / rt;
  const float crd  = -LOG2E / p_rd[0];
  const float li0  = __log2f(p_i0[0]);
  const float norm16 = 0.3989422804014327f / sig * 0.0625f;
  const float df     = (freqs[1] - freqs[0]) * 0.25f;
  const float f0     = freqs[0] - 1.5f * df;
  const float vshift = p_vs[0];
  const float abase  = 2.0f * 2.5066282746f * sig / PERIOD;  // 2*sqrt(2pi s^2)/L
  const float vlim   = fabsf(p_vmax[0]) * 0.63661977f * fabsf(si);
  const float vcut   = PERIOD - vlim - 4.5f * sig;   // valid-channel window

  // ---- table: TA/TB[k][M] = a_k*norm16 * sum_r {cos,sin}(w_k * vm_r) ----
  for (int e = t; e < (NH + 1) * NM; e += BLKT) {
    const int k = e / NM;
    const int M = e - k * NM;
    const float om = W1RAD * (float)k;
    float ck = abase * __expf(-0.5f * sig * sig * om * om);
    if (k == 0) ck *= 0.5f;                    // a0 = abase/2
    ck *= norm16;
    float sc = 0.f, sn = 0.f;
    #pragma unroll
    for (int r = 0; r < 4; ++r) {
      const float ffine = f0 + df * (float)(4 * M + r);
      const float vm = C_KMS * (F0GHZ - ffine) / F0GHZ - vshift;
      if (fabsf(vm) <= vcut) {                 // zero out-of-window channels
        sc += __cosf(om * vm);
        sn += __sinf(om * vm);
      }
    }
    TA[e] = ck * sc;
    TB[e] = ck * sn;
  }

  // ---- deposit: pixel = t/40 ----
  const int pix = t / NTPP;          // 0..7
  const int l   = t - pix * NTPP;    // 0..39
  {
    const float gx = -987.5f + 25.0f * (float)p;
    const float gy = -987.5f + 25.0f * (float)(q0 + pix);

    float accD = 0.f;
    float aR[NH], aI[NH];
    #pragma unroll
    for (int k = 0; k < NH; ++k) { aR[k] = 0.f; aI[k] = 0.f; }

    const bool refined = (gx * gx + gy * gy) < RCUT2;
    if (!refined) {
      // OUTER: one z-QUAD eval (4 fine z x 2x2 spatial = 16 cells, wgt 16)
      const float x1 = gx * cr - gy * sr;
      const float y1 = gx * sr + gy * cr;
      const float x12  = x1 * x1;
      const float gxy2 = gx * gx + gy * gy;
      const float y1ci = y1 * ci;
      const float kcolw = kfac * x1 * W1RAD;
      float ang, I16;
      CELLG(-975.0f + 50.0f * (float)l, ang, I16, 16.0f)
      const float cA = __cosf(ang), sA = __sinf(ang);
      float uR = I16 * cA, uI = I16 * sA;
      accD = I16;
      aR[0] = uR; aI[0] = uI;
      #pragma unroll
      for (int k = 1; k < NH; ++k) {
        const float tR = fmaf(uR, cA, -uI * sA);
        const float tI = fmaf(uI, cA,  uR * sA);
        uR = tR; uI = tI;
        aR[k] = uR; aI[k] = uI;
      }
    } else {
      // REFINED center: 4 sub-evals x 2 z-pair midpoints (wgt 2) — R15 path
      const int m0 = 2 * l;
      #pragma unroll
      for (int s = 0; s < 4; ++s) {
        const float gxs = gx + ((s & 1) ? 6.25f : -6.25f);
        const float gys = gy + ((s & 2) ? 6.25f : -6.25f);
        const float x1 = gxs * cr - gys * sr;
        const float y1 = gxs * sr + gys * cr;
        const float x12  = x1 * x1;
        const float gxy2 = gxs * gxs + gys * gys;
        const float y1ci = y1 * ci;
        const float kcolw = kfac * x1 * W1RAD;

        float angA, IA, angB, IB;              // 2 independent chains
        CELLG(-987.5f + 25.0f * (float)m0,       angA, IA, 2.0f)
        CELLG(-987.5f + 25.0f * (float)(m0 + 1), angB, IB, 2.0f)
        const float cA = __cosf(angA), sA = __sinf(angA);
        const float cB = __cosf(angB), sB = __sinf(angB);
        float uRA = IA * cA, uIA = IA * sA;    // I * e^{i*theta}
        float uRB = IB * cB, uIB = IB * sB;
        accD += IA + IB;
        aR[0] += uRA + uRB;
        aI[0] += uIA + uIB;
        #pragma unroll
        for (int k = 1; k < NH; ++k) {         // rotate both chains
          const float tRA = fmaf(uRA, cA, -uIA * sA);
          const float tIA = fmaf(uIA, cA,  uRA * sA);
          const float tRB = fmaf(uRB, cB, -uIB * sB);
          const float tIB = fmaf(uIB, cB,  uRB * sB);
          uRA = tRA; uIA = tIA; uRB = tRB; uIB = tIB;
          aR[k] += uRA + uRB;
          aI[k] += uIA + uIB;
        }
      }
    }

    float* rbase = &Rbuf[(pix * 29) * RST + l];
    rbase[0] = accD;
    #pragma unroll
    for (int k = 1; k <= NH; ++k) {
      rbase[(2 * k - 1) * RST] = aR[k - 1];
      rbase[(2 * k)     * RST] = aI[k - 1];
    }
  }
  __syncthreads();

  // ---- reduce: 232 rows (8 pix x 29) of 40 values each ----
  if (t < NPIXB * 29) {
    const int rpix = t / 29;
    const int h    = t - rpix * 29;
    const float4* src = (const float4*)&Rbuf[(rpix * 29 + h) * RST];
    float a0 = 0.f, a1 = 0.f, a2 = 0.f, a3 = 0.f;
    #pragma unroll
    for (int c = 0; c < 10; ++c) {             // 40 floats = 10 x float4
      const float4 v = src[c];
      a0 += v.x; a1 += v.y; a2 += v.z; a3 += v.w;
    }
    F[rpix * 32 + h] = (a0 + a1) + (a2 + a3);
  }
  __syncthreads();

  // ---- finish: each thread emits its pixel AND the inversion partner ----
  // partner (79-p, 79-q): spectrum is S(-v)  =>  acc- uses -TB terms.
  {
    const int opix = t & 7;                    // pixel
    const int M    = t >> 3;                   // channel
    const float* Fp = &F[opix * 32];
    float accP = TA[M] * Fp[0];
    float accM = accP;
    #pragma unroll
    for (int k = 1; k <= NH; ++k) {
      const float e = TA[k * NM + M] * Fp[2 * k - 1];
      const float o = TB[k * NM + M] * Fp[2 * k];
      accP += e + o;
      accM += e - o;
    }
    const int q = q0 + opix;
    out[(size_t)M * NPIXT + p * RES + q] = accP;
    out[(size_t)M * NPIXT + (RES - 1 - p) * RES + (RES - 1 - q)] = accM;
  }
}

extern "C" void kernel_launch(void* const* d_in, const int* in_sizes, int n_in,
                              void* d_out, int out_size, void* d_ws, size_t ws_size,
                              hipStream_t stream) {
  const float* p_inc   = (const float*)d_in[0];
  const float* p_rot   = (const float*)d_in[1];
  const float* p_lb    = (const float*)d_in[2];
  const float* p_vs    = (const float*)d_in[3];
  const float* p_vmax  = (const float*)d_in[4];
  const float* p_rturn = (const float*)d_in[5];
  const float* p_i0    = (const float*)d_in[6];
  const float* p_rd    = (const float*)d_in[7];
  const float* freqs   = (const float*)d_in[8];
  float* out = (float*)d_out;

  hipLaunchKernelGGL(fourier_kernel, dim3(NPIXT / NPIXB / 2), dim3(BLKT),
                     0, stream, p_inc, p_rot, p_lb, p_vs, p_vmax, p_rturn,
                     p_i0, p_rd, freqs, out);
}

// Round 18
// 13.881 us; speedup vs baseline: 1.1281x; 1.1281x over previous
//
#include <hip/hip_runtime.h>
#include <hip/hip_bf16.h>
#include <math.h>

// ThickCubeSimulator R17 == R15 (verbatim revert; R16's outer z-quad merge
// regressed 13.70 -> 15.66 us from wave-divergence + de-ILP'd chains).
//  Final structure: Fourier-space deposit (no LDS atomics), z-pair merge,
//  spatial 2x2 merge with central refinement (<350 pc), exact inversion
//  symmetry (half grid computed, partner = conjugate spectrum).
//  Floor accounting: ~10us launch/dispatch + ~1.5us deposit issue + ~2us
//  table/reduce/finish. Work cuts below ~2us of issue no longer move dur.

#define RES   80
#define NM    40
#define NPIXT (RES*RES)
#define NPIXB 8            // coarse pixels per block
#define NTPP  40           // threads per pixel
#define BLKT  320          // block size
#define NH    14           // harmonics (k=1..14) + DC -> 29 accumulators
#define RST   44           // Rbuf row stride (floats): 40 + pad, 16B multiple
#define RCUT2 (350.0f * 350.0f)  // refinement radius^2 (sky plane, pc^2)
#define C_KMS 299792.458f
#define F0GHZ 230.538f
#define LOG2E 1.44269504088896340736f
#define HPI   1.57079632679489662f
#define W1RAD 0.00981747704f     // 2*pi / 640 (rad per km/s)
#define PERIOD 640.0f

__device__ __forceinline__ float fast_exp2(float x) {
#if __has_builtin(__builtin_amdgcn_exp2f)
  return __builtin_amdgcn_exp2f(x);
#else
  return exp2f(x);
#endif
}
__device__ __forceinline__ float fast_rcp(float x) {
#if __has_builtin(__builtin_amdgcn_rcpf)
  return __builtin_amdgcn_rcpf(x);
#else
  return 1.0f / x;
#endif
}

// atan(u) for u>=0 via t=min(u,1/u) in [0,1], poly err ~1e-6 rad
__device__ __forceinline__ float atan_pos(float u, float uinv) {
  const float t  = fminf(u, uinv);
  const float t2 = t * t;
  float p = fmaf(t2, -0.0117212f, 0.05265332f);
  p = fmaf(t2, p, -0.11643287f);
  p = fmaf(t2, p, 0.19354346f);
  p = fmaf(t2, p, -0.33262347f);
  p = fmaf(t2, p, 0.99997726f);
  const float a = t * p;
  return (u <= 1.0f) ? a : (HPI - a);
}

// per-eval math at (gxs, gys), z-pair midpoint m (gz = -987.5 + 25*m):
//   IO = wgt * I(point); wgt = 8 (merged) or 2 (refined sub-pixel)
#define CELLW(mm, ANGO, IO) {                               \
    const float gz = -987.5f + 25.0f * (float)(mm);         \
    const float ry = fmaf(-si, gz, y1ci);                   \
    const float s2 = fmaf(ry, ry, x12);                     \
    const float rq = sqrtf(s2);                             \
    const float ri = fast_rcp(fmaxf(rq, 1e-30f));           \
    const float at = atan_pos(rq * irt, rt * ri);           \
    const float rs = sqrtf(fmaf(gz, gz, gxy2));             \
    ANGO = kcolw * (ri * at);                               \
    IO = wgt * fast_exp2(fmaf(rs, crd, li0)); }

__global__ __launch_bounds__(BLKT) void fourier_kernel(
    const float* __restrict__ p_inc, const float* __restrict__ p_rot,
    const float* __restrict__ p_lb,  const float* __restrict__ p_vs,
    const float* __restrict__ p_vmax, const float* __restrict__ p_rturn,
    const float* __restrict__ p_i0,  const float* __restrict__ p_rd,
    const float* __restrict__ freqs, float* __restrict__ out)
{
  __shared__ float TA[(NH + 1) * NM];          // 600 floats
  __shared__ float TB[(NH + 1) * NM];          // 600 floats
  __shared__ __align__(16) float Rbuf[NPIXB * 29 * RST];   // 10208 floats
  __shared__ float F[NPIXB * 32];              // reduced coeffs per pixel

  const int t   = threadIdx.x;
  const int blk = blockIdx.x;                  // 0..399
  const int p   = blk / (RES / NPIXB);         // coarse row 0..39 (half grid)
  const int q0  = (blk - p * (RES / NPIXB)) * NPIXB;

  // ---- per-thread params (uniform small args -> fast trig) ----
  const float inc = p_inc[0], rotv = p_rot[0], sig = p_lb[0];
  const float si = __sinf(inc), ci = __cosf(inc);
  const float cr = __cosf(rotv), sr = __sinf(rotv);
  const float kfac = -p_vmax[0] * 0.63661977236758134f * si;
  const float rt   = p_rturn[0];
  const float irt  = 1.0f / rt;
  const float crd  = -LOG2E / p_rd[0];
  const float li0  = __log2f(p_i0[0]);
  const float norm16 = 0.3989422804014327f / sig * 0.0625f;
  const float df     = (freqs[1] - freqs[0]) * 0.25f;
  const float f0     = freqs[0] - 1.5f * df;
  const float vshift = p_vs[0];
  const float abase  = 2.0f * 2.5066282746f * sig / PERIOD;  // 2*sqrt(2pi s^2)/L
  const float vlim   = fabsf(p_vmax[0]) * 0.63661977f * fabsf(si);
  const float vcut   = PERIOD - vlim - 4.5f * sig;   // valid-channel window

  // ---- table: TA/TB[k][M] = a_k*norm16 * sum_r {cos,sin}(w_k * vm_r) ----
  for (int e = t; e < (NH + 1) * NM; e += BLKT) {
    const int k = e / NM;
    const int M = e - k * NM;
    const float om = W1RAD * (float)k;
    float ck = abase * __expf(-0.5f * sig * sig * om * om);
    if (k == 0) ck *= 0.5f;                    // a0 = abase/2
    ck *= norm16;
    float sc = 0.f, sn = 0.f;
    #pragma unroll
    for (int r = 0; r < 4; ++r) {
      const float ffine = f0 + df * (float)(4 * M + r);
      const float vm = C_KMS * (F0GHZ - ffine) / F0GHZ - vshift;
      if (fabsf(vm) <= vcut) {                 // zero out-of-window channels
        sc += __cosf(om * vm);
        sn += __sinf(om * vm);
      }
    }
    TA[e] = ck * sc;
    TB[e] = ck * sn;
  }

  // ---- deposit: pixel = t/40; thread does z-pair midpoints m=2l, 2l+1 ----
  const int pix = t / NTPP;          // 0..7
  const int l   = t - pix * NTPP;    // 0..39
  {
    const float gx = -987.5f + 25.0f * (float)p;
    const float gy = -987.5f + 25.0f * (float)(q0 + pix);
    const int m0 = 2 * l;

    float accD = 0.f;
    float aR[NH], aI[NH];
    #pragma unroll
    for (int k = 0; k < NH; ++k) { aR[k] = 0.f; aI[k] = 0.f; }

    // refine central pixels: 4 sub-evals at fine-pixel centers (weight 2);
    // outer pixels: 1 merged eval at coarse center (weight 8)
    const bool refined = (gx * gx + gy * gy) < RCUT2;
    const int   nsub = refined ? 4 : 1;
    const float wgt  = refined ? 2.0f : 8.0f;

    for (int s = 0; s < nsub; ++s) {
      const float gxs = refined ? (gx + ((s & 1) ? 6.25f : -6.25f)) : gx;
      const float gys = refined ? (gy + ((s & 2) ? 6.25f : -6.25f)) : gy;
      const float x1 = gxs * cr - gys * sr;
      const float y1 = gxs * sr + gys * cr;
      const float x12  = x1 * x1;
      const float gxy2 = gxs * gxs + gys * gys;
      const float y1ci = y1 * ci;
      const float kcolw = kfac * x1 * W1RAD;   // theta = kcolw * (ri*at)

      float angA, IA, angB, IB;                // 2 independent chains
      CELLW(m0,     angA, IA)
      CELLW(m0 + 1, angB, IB)
      const float cA = __cosf(angA), sA = __sinf(angA);
      const float cB = __cosf(angB), sB = __sinf(angB);
      float uRA = IA * cA, uIA = IA * sA;      // I * e^{i*theta}
      float uRB = IB * cB, uIB = IB * sB;
      accD += IA + IB;
      aR[0] += uRA + uRB;
      aI[0] += uIA + uIB;
      #pragma unroll
      for (int k = 1; k < NH; ++k) {           // rotate both chains
        const float tRA = fmaf(uRA, cA, -uIA * sA);
        const float tIA = fmaf(uIA, cA,  uRA * sA);
        const float tRB = fmaf(uRB, cB, -uIB * sB);
        const float tIB = fmaf(uIB, cB,  uRB * sB);
        uRA = tRA; uIA = tIA; uRB = tRB; uIB = tIB;
        aR[k] += uRA + uRB;
        aI[k] += uIA + uIB;
      }
    }

    float* rbase = &Rbuf[(pix * 29) * RST + l];
    rbase[0] = accD;
    #pragma unroll
    for (int k = 1; k <= NH; ++k) {
      rbase[(2 * k - 1) * RST] = aR[k - 1];
      rbase[(2 * k)     * RST] = aI[k - 1];
    }
  }
  __syncthreads();

  // ---- reduce: 232 rows (8 pix x 29) of 40 values each ----
  if (t < NPIXB * 29) {
    const int rpix = t / 29;
    const int h    = t - rpix * 29;
    const float4* src = (const float4*)&Rbuf[(rpix * 29 + h) * RST];
    float a0 = 0.f, a1 = 0.f, a2 = 0.f, a3 = 0.f;
    #pragma unroll
    for (int c = 0; c < 10; ++c) {             // 40 floats = 10 x float4
      const float4 v = src[c];
      a0 += v.x; a1 += v.y; a2 += v.z; a3 += v.w;
    }
    F[rpix * 32 + h] = (a0 + a1) + (a2 + a3);
  }
  __syncthreads();

  // ---- finish: each thread emits its pixel AND the inversion partner ----
  // partner (79-p, 79-q): spectrum is S(-v)  =>  acc- uses -TB terms.
  {
    const int opix = t & 7;                    // pixel
    const int M    = t >> 3;                   // channel
    const float* Fp = &F[opix * 32];
    float accP = TA[M] * Fp[0];
    float accM = accP;
    #pragma unroll
    for (int k = 1; k <= NH; ++k) {
      const float e = TA[k * NM + M] * Fp[2 * k - 1];
      const float o = TB[k * NM + M] * Fp[2 * k];
      accP += e + o;
      accM += e - o;
    }
    const int q = q0 + opix;
    out[(size_t)M * NPIXT + p * RES + q] = accP;
    out[(size_t)M * NPIXT + (RES - 1 - p) * RES + (RES - 1 - q)] = accM;
  }
}

extern "C" void kernel_launch(void* const* d_in, const int* in_sizes, int n_in,
                              void* d_out, int out_size, void* d_ws, size_t ws_size,
                              hipStream_t stream) {
  const float* p_inc   = (const float*)d_in[0];
  const float* p_rot   = (const float*)d_in[1];
  const float* p_lb    = (const float*)d_in[2];
  const float* p_vs    = (const float*)d_in[3];
  const float* p_vmax  = (const float*)d_in[4];
  const float* p_rturn = (const float*)d_in[5];
  const float* p_i0    = (const float*)d_in[6];
  const float* p_rd    = (const float*)d_in[7];
  const float* freqs   = (const float*)d_in[8];
  float* out = (float*)d_out;

  hipLaunchKernelGGL(fourier_kernel, dim3(NPIXT / NPIXB / 2), dim3(BLKT),
                     0, stream, p_inc, p_rot, p_lb, p_vs, p_vmax, p_rturn,
                     p_i0, p_rd, freqs, out);
}